// Round 1
// baseline (584.819 us; speedup 1.0000x reference)
//
#include <hip/hip_runtime.h>
#include <hip/hip_bf16.h>

// SparseFFN: B=4, L=4096, D=1024, E=64, CHUNK=128 -> 128 chunks, top-2 experts.
// Pipeline: router (fp64) -> x->bf16 cvt (ws) -> 128x128-tile bf16 MFMA GEMM,
// both experts accumulated in AGPRs, *0.5 in epilogue.

#define BD 4
#define LD 4096
#define DD 1024
#define ED 64
#define CHUNKD 128
#define NBITS 6
#define NCHUNK 128   // B * L/CHUNK

typedef __bf16 bf16_8 __attribute__((ext_vector_type(8)));
typedef __bf16 bf16_4 __attribute__((ext_vector_type(4)));
typedef float floatx4 __attribute__((ext_vector_type(4)));

// ---------------- router: chunk mean -> proj[6] -> (e1, e2) ----------------
__global__ __launch_bounds__(256) void router_kernel(
    const float* __restrict__ x, const float* __restrict__ hyp,
    int* __restrict__ eidx)
{
    const int chunk = blockIdx.x;            // 0..127
    const int t = threadIdx.x;               // 256 threads, 4 dims each
    const float* xc = x + (size_t)chunk * CHUNKD * DD;

    double cs[4] = {0.0, 0.0, 0.0, 0.0};
    for (int tok = 0; tok < CHUNKD; ++tok) {
        const float* row = xc + tok * DD;
        #pragma unroll
        for (int i = 0; i < 4; ++i) cs[i] += (double)row[t + i * 256];
    }
    double pj[NBITS];
    #pragma unroll
    for (int j = 0; j < NBITS; ++j) pj[j] = 0.0;
    #pragma unroll
    for (int i = 0; i < 4; ++i) {
        const int d = t + i * 256;
        const double emb = cs[i] * (1.0 / 128.0);
        #pragma unroll
        for (int j = 0; j < NBITS; ++j)
            pj[j] += emb * (double)hyp[d * NBITS + j];
    }
    // wave(64) shuffle reduce, then LDS combine of 4 waves
    #pragma unroll
    for (int off = 32; off > 0; off >>= 1) {
        #pragma unroll
        for (int j = 0; j < NBITS; ++j)
            pj[j] += __shfl_down(pj[j], off, 64);
    }
    __shared__ double red[4][NBITS];
    const int wave = t >> 6, lane = t & 63;
    if (lane == 0) {
        #pragma unroll
        for (int j = 0; j < NBITS; ++j) red[wave][j] = pj[j];
    }
    __syncthreads();
    if (t == 0) {
        int e1 = 0, weakest = 0;
        double best = 1e300;
        #pragma unroll
        for (int j = 0; j < NBITS; ++j) {
            double p = red[0][j] + red[1][j] + red[2][j] + red[3][j];
            if (p > 0.0) e1 |= (1 << j);
            double a = fabs(p);
            if (a < best) { best = a; weakest = j; }  // first-min, like argmin
        }
        eidx[chunk * 2 + 0] = e1;
        eidx[chunk * 2 + 1] = e1 ^ (1 << weakest);
    }
}

// ---------------- x (fp32) -> A (bf16) ----------------
__global__ __launch_bounds__(256) void cvt_x_kernel(
    const float* __restrict__ x, __bf16* __restrict__ a)
{
    const size_t i = ((size_t)blockIdx.x * 256 + threadIdx.x) * 4;
    const float4 v = *(const float4*)(x + i);
    bf16_4 o;
    o[0] = (__bf16)v.x; o[1] = (__bf16)v.y; o[2] = (__bf16)v.z; o[3] = (__bf16)v.w;
    *(bf16_4*)(a + i) = o;
}

// ---------------- GEMM: out[chunk] = 0.5*(A@W[e1] + A@W[e2]) ----------------
// grid = 128 chunks * 8 n-tiles. 256 threads = 4 waves, each 64x64 of 128x128.
__global__ __launch_bounds__(256) void ffn_gemm(
    const __bf16* __restrict__ Abf,      // [NCHUNK*128, 1024] bf16 (ws)
    const float* __restrict__ W,         // [64, 1024, 1024] fp32
    const int* __restrict__ eidx,        // [NCHUNK][2]
    float* __restrict__ out)             // [NCHUNK*128, 1024] fp32
{
    __shared__ __bf16 Als[128 * 32];     // A tile [m][k], row 64B
    __shared__ __bf16 Bls[128 * 32];     // B tile transposed [n][k], row 64B

    const int bx = blockIdx.x;
    const int chunk = bx >> 3;
    const int n0 = (bx & 7) * 128;
    const int t = threadIdx.x;
    const int lane = t & 63;
    const int wave = t >> 6;
    const int wm = wave >> 1;            // wave row 0..1 (64 rows each)
    const int wn = wave & 1;             // wave col 0..1
    const int lr = lane & 15;
    const int q  = lane >> 4;            // quad 0..3

    const int e0 = eidx[chunk * 2 + 0];
    const int e1 = eidx[chunk * 2 + 1];
    const int ee[2] = {e0, e1};

    const __bf16* Ag = Abf + (size_t)chunk * CHUNKD * DD;
    // A async staging: issue i of wave -> rows (wave*2+i)*16 + lane/4, cols (lane&3)*8
    const int a_col = (lane & 3) * 8;
    const int a_rsub = lane >> 2;

    floatx4 acc[4][4] = {};

    for (int xp = 0; xp < 2; ++xp) {
        const float* We = W + (size_t)ee[xp] * (DD * DD) + n0;
        for (int k0 = 0; k0 < DD; k0 += 32) {
            // ---- B: 16 fp32 global loads per thread (k-strided, lane-coalesced)
            float bv[2][8];
            #pragma unroll
            for (int rep = 0; rep < 2; ++rep) {
                const int nb = wave * 16 + lr + rep * 64;
                const float* src = We + (size_t)(k0 + q * 8) * DD + nb;
                #pragma unroll
                for (int j = 0; j < 8; ++j) bv[rep][j] = src[(size_t)j * DD];
            }
            // ---- A: async global->LDS, 16B/lane, wave-uniform LDS base
            #pragma unroll
            for (int i = 0; i < 2; ++i) {
                const __bf16* ga = Ag + (size_t)((wave * 2 + i) * 16 + a_rsub) * DD + k0 + a_col;
                __builtin_amdgcn_global_load_lds(
                    (const __attribute__((address_space(1))) void*)ga,
                    (__attribute__((address_space(3))) void*)(&Als[(wave * 2 + i) * 512]),
                    16, 0, 0);
            }
            // ---- B: cvt + transposed LDS write (all 32 banks covered -> no conflict)
            #pragma unroll
            for (int rep = 0; rep < 2; ++rep) {
                const int nb = wave * 16 + lr + rep * 64;
                bf16_8 bw;
                #pragma unroll
                for (int j = 0; j < 8; ++j) bw[j] = (__bf16)bv[rep][j];
                *(bf16_8*)(&Bls[nb * 32 + q * 8]) = bw;
            }
            __syncthreads();

            // ---- fragments + 16 MFMAs
            bf16_8 af[4], bf[4];
            #pragma unroll
            for (int mt = 0; mt < 4; ++mt)
                af[mt] = *(const bf16_8*)(&Als[(wm * 64 + mt * 16 + lr) * 32 + q * 8]);
            #pragma unroll
            for (int nt = 0; nt < 4; ++nt)
                bf[nt] = *(const bf16_8*)(&Bls[(wn * 64 + nt * 16 + lr) * 32 + q * 8]);
            #pragma unroll
            for (int mt = 0; mt < 4; ++mt) {
                #pragma unroll
                for (int nt = 0; nt < 4; ++nt)
                    acc[mt][nt] = __builtin_amdgcn_mfma_f32_16x16x32_bf16(
                        af[mt], bf[nt], acc[mt][nt], 0, 0, 0);
            }
            __syncthreads();
        }
    }

    // ---- epilogue: C/D layout col=lane&15, row=quad*4+reg; scale 0.5
    const size_t orow0 = (size_t)chunk * CHUNKD;
    #pragma unroll
    for (int mt = 0; mt < 4; ++mt) {
        #pragma unroll
        for (int nt = 0; nt < 4; ++nt) {
            const int col = n0 + wn * 64 + nt * 16 + lr;
            #pragma unroll
            for (int r = 0; r < 4; ++r) {
                const int row = wm * 64 + mt * 16 + q * 4 + r;
                out[(orow0 + row) * DD + col] = acc[mt][nt][r] * 0.5f;
            }
        }
    }
}

extern "C" void kernel_launch(void* const* d_in, const int* in_sizes, int n_in,
                              void* d_out, int out_size, void* d_ws, size_t ws_size,
                              hipStream_t stream) {
    const float* x   = (const float*)d_in[0];   // [4,4096,1024]
    const float* W   = (const float*)d_in[1];   // [64,1024,1024]
    const float* hyp = (const float*)d_in[2];   // [1024,6]
    float* out = (float*)d_out;

    int* eidx = (int*)d_ws;                              // 256 ints
    __bf16* Abf = (__bf16*)((char*)d_ws + 1024);         // 33.6 MB bf16 A

    router_kernel<<<NCHUNK, 256, 0, stream>>>(x, hyp, eidx);
    cvt_x_kernel<<<(BD * LD * DD) / (256 * 4), 256, 0, stream>>>(x, Abf);
    ffn_gemm<<<NCHUNK * 8, 256, 0, stream>>>(Abf, W, eidx, out);
}